// Round 9
// baseline (1299.338 us; speedup 1.0000x reference)
//
#include <hip/hip_runtime.h>

#define NN 100000
#define NE 1600000
#define DF 32
#define KIT 5
#define MU 0.01f
#define NSLOT 256
#define NV4 (NN * DF / 4)

#define SCAN_CHUNK 1024
#define SCAN_NB ((NN + SCAN_CHUNK - 1) / SCAN_CHUNK)  // 98 blocks

#define BROWS 512
#define NBUCKET ((NN + BROWS - 1) / BROWS)            // 196 buckets

// ---------- one-time CSR build (row is iteration-invariant) ----------

__global__ __launch_bounds__(256) void zero_deg_kernel(int* __restrict__ deg) {
    int i = blockIdx.x * blockDim.x + threadIdx.x;
    if (i < NN) deg[i] = 0;
}

__global__ __launch_bounds__(256) void hist_kernel(const int* __restrict__ row,
                                                   int* __restrict__ deg) {
    int e = blockIdx.x * blockDim.x + threadIdx.x;
    if (e < NE) atomicAdd(&deg[row[e]], 1);
}

__global__ __launch_bounds__(256) void blocksum_kernel(const int* __restrict__ deg,
                                                       int* __restrict__ bsum) {
    const int t = threadIdx.x;
    const int base = blockIdx.x * SCAN_CHUNK + t * 4;
    int s = 0;
    #pragma unroll
    for (int i = 0; i < 4; ++i) {
        int idx = base + i;
        if (idx < NN) s += deg[idx];
    }
    #pragma unroll
    for (int m = 32; m > 0; m >>= 1) s += __shfl_xor(s, m, 64);
    __shared__ int sm[4];
    if ((t & 63) == 0) sm[t >> 6] = s;
    __syncthreads();
    if (t == 0) bsum[blockIdx.x] = sm[0] + sm[1] + sm[2] + sm[3];
}

__global__ __launch_bounds__(128) void scanbsum_kernel(int* __restrict__ bsum) {
    __shared__ int sh[SCAN_NB];
    const int t = threadIdx.x;
    if (t < SCAN_NB) sh[t] = bsum[t];
    __syncthreads();
    if (t == 0) {
        int run = 0;
        for (int i = 0; i < SCAN_NB; ++i) {
            int v = sh[i];
            sh[i] = run;
            run += v;
        }
    }
    __syncthreads();
    if (t < SCAN_NB) bsum[t] = sh[t];
}

__global__ __launch_bounds__(256) void scanfinal_kernel(const int* __restrict__ deg,
                                                        const int* __restrict__ bsum,
                                                        int* __restrict__ rowptr) {
    const int t = threadIdx.x;
    const int base = blockIdx.x * SCAN_CHUNK + t * 4;
    int d[4];
    int s = 0;
    #pragma unroll
    for (int i = 0; i < 4; ++i) {
        int idx = base + i;
        d[i] = (idx < NN) ? deg[idx] : 0;
        s += d[i];
    }
    __shared__ int sh[256];
    sh[t] = s;
    __syncthreads();
    for (int off = 1; off < 256; off <<= 1) {
        int v = (t >= off) ? sh[t - off] : 0;
        __syncthreads();
        sh[t] += v;
        __syncthreads();
    }
    int run = bsum[blockIdx.x] + sh[t] - s;
    #pragma unroll
    for (int i = 0; i < 4; ++i) {
        int idx = base + i;
        if (idx < NN) {
            rowptr[idx] = run;
            run += d[i];
        }
    }
    if (blockIdx.x == 0 && t == 0) rowptr[NN] = NE;
}

__global__ __launch_bounds__(256) void bcur_init_kernel(const int* __restrict__ rowptr,
                                                        int* __restrict__ bcur) {
    int i = blockIdx.x * blockDim.x + threadIdx.x;
    if (i < NBUCKET) bcur[i] = rowptr[i * BROWS];
}

// pass1: append (rlow,col) packed into the bucket's segment of packed[].
// Append-only per bucket -> ~196 hot cachelines, writes stream (no L2 thrash).
__global__ __launch_bounds__(256) void bucket_fill_kernel(const int* __restrict__ row,
                                                          const int* __restrict__ col,
                                                          int* __restrict__ bcur,
                                                          unsigned int* __restrict__ packed) {
    int e = blockIdx.x * blockDim.x + threadIdx.x;
    if (e < NE) {
        const int r = row[e];
        const int c = col[e];
        const int b = r >> 9;  // BROWS = 512
        const int pos = atomicAdd(&bcur[b], 1);
        packed[pos] = ((unsigned int)(r & (BROWS - 1)) << 17) | (unsigned int)c;
    }
}

// pass2: one WG per bucket. Scatter cols to their row positions within the
// bucket's segment (segment ~32KB, L2-resident; LDS cursors per row).
__global__ __launch_bounds__(256) void bucket_sort_kernel(const int* __restrict__ rowptr,
                                                          const unsigned int* __restrict__ packed,
                                                          int* __restrict__ colsorted) {
    const int b = blockIdx.x;
    const int base = b * BROWS;
    const int rows = min(BROWS, NN - base);
    const int segbase = rowptr[base];
    const int segend = rowptr[base + rows];
    __shared__ int cur[BROWS];
    for (int i = threadIdx.x; i < rows; i += 256) cur[i] = rowptr[base + i] - segbase;
    __syncthreads();
    for (int j = segbase + threadIdx.x; j < segend; j += 256) {
        const unsigned int p = packed[j];
        const int rl = p >> 17;
        const int c = (int)(p & 0x1FFFFu);
        const int pos = atomicAdd(&cur[rl], 1);
        colsorted[segbase + pos] = c;
    }
}

// ---------- bf16 shadow helpers ----------

__device__ __forceinline__ unsigned int pack2bf(float a, float b) {
    unsigned int ua = __float_as_uint(a);
    unsigned int ub = __float_as_uint(b);
    return ((ua + 0x8000u) >> 16) | (((ub + 0x8000u) >> 16) << 16);
}

__device__ __forceinline__ void unpack8(uint4 v, float* f) {
    f[0] = __uint_as_float(v.x << 16);
    f[1] = __uint_as_float(v.x & 0xffff0000u);
    f[2] = __uint_as_float(v.y << 16);
    f[3] = __uint_as_float(v.y & 0xffff0000u);
    f[4] = __uint_as_float(v.z << 16);
    f[5] = __uint_as_float(v.z & 0xffff0000u);
    f[6] = __uint_as_float(v.w << 16);
    f[7] = __uint_as_float(v.w & 0xffff0000u);
}

__global__ __launch_bounds__(256) void tobf16_kernel(const float4* __restrict__ h,
                                                     uint2* __restrict__ hb) {
    int i = blockIdx.x * blockDim.x + threadIdx.x;
    if (i < NV4) {
        const float4 v = h[i];
        hb[i] = make_uint2(pack2bf(v.x, v.y), pack2bf(v.z, v.w));
    }
}

// ---------- per-iteration ----------

// One 32-lane group per NODE PAIR. lane = q(3b)*4 + f2(2b); a quad of lanes
// covers one 64B bf16 row (uint4/lane). All 10 loads for both nodes (2 col
// vectors, 2 own rows, 8 batch gathers) are issued before any consumption ->
// ~10 vmem in flight per group. First 32 edges of each node via one batch;
// deg>32 tail loops (rare at Poisson(16)).
__global__ __launch_bounds__(256) void agg_kernel(const uint4* __restrict__ hb4,
                                                  const int* __restrict__ rowptr,
                                                  const int* __restrict__ colsorted,
                                                  float* __restrict__ S,
                                                  int* __restrict__ maxslots) {
    const int lane = threadIdx.x & 31;
    const int q = lane >> 2;
    const int f2 = lane & 3;
    const int pair = (blockIdx.x * blockDim.x + threadIdx.x) >> 5;
    const int n0 = pair * 2;
    const int n1 = n0 + 1;

    const int s0 = rowptr[n0];
    const int e0 = rowptr[n0 + 1];
    const int e1 = rowptr[n0 + 2];

    // issue all independent head loads
    const int i0 = s0 + lane;
    const int i1 = e0 + lane;
    const int ca = (i0 < e0) ? colsorted[i0] : n0;
    const int cb = (i1 < e1) ? colsorted[i1] : n1;
    const uint4 hru0 = hb4[n0 * 4 + f2];
    const uint4 hru1 = hb4[n1 * 4 + f2];

    // batch gathers for node0 then node1 (8 loads total)
    uint4 u0[4], u1[4];
    #pragma unroll
    for (int j = 0; j < 4; ++j) u0[j] = hb4[__shfl(ca, 8 * j + q, 32) * 4 + f2];
    #pragma unroll
    for (int j = 0; j < 4; ++j) u1[j] = hb4[__shfl(cb, 8 * j + q, 32) * 4 + f2];

    float hr0[8], hr1[8];
    unpack8(hru0, hr0);
    unpack8(hru1, hr1);

    float acc0[8], acc1[8];
    #pragma unroll
    for (int i = 0; i < 8; ++i) { acc0[i] = 0.0f; acc1[i] = 0.0f; }
    float nmax = 0.0f;

    // ---- node0 batch ----
    #pragma unroll
    for (int j = 0; j < 4; ++j) {
        float d[8];
        unpack8(u0[j], d);
        float s = 0.0f;
        #pragma unroll
        for (int i = 0; i < 8; ++i) {
            d[i] = hr0[i] - d[i];
            s = fmaf(d[i], d[i], s);
        }
        s += __shfl_xor(s, 1, 32);
        s += __shfl_xor(s, 2, 32);
        const float n = fmaxf(sqrtf(s), 1e-6f);
        nmax = fmaxf(nmax, n);
        const float w = rsqrtf(n);
        #pragma unroll
        for (int i = 0; i < 8; ++i) acc0[i] = fmaf(-d[i], w, acc0[i]);
    }
    // ---- node1 batch ----
    #pragma unroll
    for (int j = 0; j < 4; ++j) {
        float d[8];
        unpack8(u1[j], d);
        float s = 0.0f;
        #pragma unroll
        for (int i = 0; i < 8; ++i) {
            d[i] = hr1[i] - d[i];
            s = fmaf(d[i], d[i], s);
        }
        s += __shfl_xor(s, 1, 32);
        s += __shfl_xor(s, 2, 32);
        const float n = fmaxf(sqrtf(s), 1e-6f);
        nmax = fmaxf(nmax, n);
        const float w = rsqrtf(n);
        #pragma unroll
        for (int i = 0; i < 8; ++i) acc1[i] = fmaf(-d[i], w, acc1[i]);
    }

    // ---- rare tails (deg > 32) ----
    for (int k = s0 + 32; k < e0; k += 8) {
        const int ei = k + q;
        const int c = (ei < e0) ? colsorted[ei] : n0;
        const uint4 uu = hb4[c * 4 + f2];
        float d[8];
        unpack8(uu, d);
        float s = 0.0f;
        #pragma unroll
        for (int i = 0; i < 8; ++i) {
            d[i] = hr0[i] - d[i];
            s = fmaf(d[i], d[i], s);
        }
        s += __shfl_xor(s, 1, 32);
        s += __shfl_xor(s, 2, 32);
        const float n = fmaxf(sqrtf(s), 1e-6f);
        nmax = fmaxf(nmax, n);
        const float w = rsqrtf(n);
        #pragma unroll
        for (int i = 0; i < 8; ++i) acc0[i] = fmaf(-d[i], w, acc0[i]);
    }
    for (int k = e0 + 32; k < e1; k += 8) {
        const int ei = k + q;
        const int c = (ei < e1) ? colsorted[ei] : n1;
        const uint4 uu = hb4[c * 4 + f2];
        float d[8];
        unpack8(uu, d);
        float s = 0.0f;
        #pragma unroll
        for (int i = 0; i < 8; ++i) {
            d[i] = hr1[i] - d[i];
            s = fmaf(d[i], d[i], s);
        }
        s += __shfl_xor(s, 1, 32);
        s += __shfl_xor(s, 2, 32);
        const float n = fmaxf(sqrtf(s), 1e-6f);
        nmax = fmaxf(nmax, n);
        const float w = rsqrtf(n);
        #pragma unroll
        for (int i = 0; i < 8; ++i) acc1[i] = fmaf(-d[i], w, acc1[i]);
    }

    // cross-quad reduce (quads hold different edges, same feats)
    #pragma unroll
    for (int m = 4; m < 32; m <<= 1) {
        #pragma unroll
        for (int i = 0; i < 8; ++i) {
            acc0[i] += __shfl_xor(acc0[i], m, 32);
            acc1[i] += __shfl_xor(acc1[i], m, 32);
        }
    }
    if (q == 0) {
        ((float4*)S)[n0 * 8 + f2 * 2] = make_float4(acc0[0], acc0[1], acc0[2], acc0[3]);
        ((float4*)S)[n0 * 8 + f2 * 2 + 1] = make_float4(acc0[4], acc0[5], acc0[6], acc0[7]);
        ((float4*)S)[n1 * 8 + f2 * 2] = make_float4(acc1[0], acc1[1], acc1[2], acc1[3]);
        ((float4*)S)[n1 * 8 + f2 * 2 + 1] = make_float4(acc1[4], acc1[5], acc1[6], acc1[7]);
    }

    // group max -> wave max -> spread atomic
    nmax = fmaxf(nmax, __shfl_xor(nmax, 4, 32));
    nmax = fmaxf(nmax, __shfl_xor(nmax, 8, 32));
    nmax = fmaxf(nmax, __shfl_xor(nmax, 16, 32));
    nmax = fmaxf(nmax, __shfl_xor(nmax, 32, 64));
    if ((threadIdx.x & 63) == 0) {
        // positive floats order like ints; 0xAA poison is negative -> loses
        atomicMax(&maxslots[blockIdx.x & (NSLOT - 1)], __float_as_int(nmax));
    }
}

// h_out = h_in - MU*sqrt(M)*S (fp32), plus refresh of the bf16 shadow.
__global__ __launch_bounds__(256) void update_kernel(const float4* __restrict__ hcur,
                                                     float4* __restrict__ hnxt,
                                                     uint2* __restrict__ hb,
                                                     const float4* __restrict__ S,
                                                     const int* __restrict__ slots) {
    const int t = threadIdx.x;
    int v = slots[t];
    #pragma unroll
    for (int m = 32; m > 0; m >>= 1) v = max(v, __shfl_xor(v, m, 64));
    __shared__ int sm[4];
    __shared__ float sscale;
    if ((t & 63) == 0) sm[t >> 6] = v;
    __syncthreads();
    if (t == 0) {
        int bm = max(max(sm[0], sm[1]), max(sm[2], sm[3]));
        sscale = MU * sqrtf(__int_as_float(bm));
    }
    __syncthreads();
    const float scale = sscale;
    const int i = blockIdx.x * blockDim.x + t;
    if (i < NV4) {
        const float4 hv = hcur[i];
        const float4 sv = S[i];
        float4 o;
        o.x = hv.x - scale * sv.x;
        o.y = hv.y - scale * sv.y;
        o.z = hv.z - scale * sv.z;
        o.w = hv.w - scale * sv.w;
        hnxt[i] = o;
        hb[i] = make_uint2(pack2bf(o.x, o.y), pack2bf(o.z, o.w));
    }
}

extern "C" void kernel_launch(void* const* d_in, const int* in_sizes, int n_in,
                              void* d_out, int out_size, void* d_ws, size_t ws_size,
                              hipStream_t stream) {
    const float* h_in = (const float*)d_in[0];
    const int* row = (const int*)d_in[1];
    const int* col = row + NE;
    float* out = (float*)d_out;

    float* S = (float*)d_ws;                        // NN*DF f32
    int* maxslots = (int*)(S + NN * DF);            // KIT*NSLOT
    int* deg = maxslots + KIT * NSLOT;              // NN
    int* rowptr = deg + NN;                         // NN+1
    int* bsum = rowptr + NN + 1;                    // SCAN_NB
    int* bcur = bsum + SCAN_NB;                     // NBUCKET
    unsigned int* packed = (unsigned int*)(bcur + NBUCKET);  // NE
    int* colsorted = (int*)(packed + NE);           // NE
    uintptr_t p = (uintptr_t)(colsorted + NE);
    p = (p + 15) & ~(uintptr_t)15;
    uint2* hb = (uint2*)p;                          // NN*DF bf16 = 6.4 MB

    const int eb = (NE + 255) / 256;
    const int nb = (NN + 255) / 256;
    const int gb = (NN / 2 * 32 + 255) / 256;       // 6250
    const int ub = (NV4 + 255) / 256;               // 3125

    zero_deg_kernel<<<nb, 256, 0, stream>>>(deg);
    hist_kernel<<<eb, 256, 0, stream>>>(row, deg);
    blocksum_kernel<<<SCAN_NB, 256, 0, stream>>>(deg, bsum);
    scanbsum_kernel<<<1, 128, 0, stream>>>(bsum);
    scanfinal_kernel<<<SCAN_NB, 256, 0, stream>>>(deg, bsum, rowptr);
    bcur_init_kernel<<<1, 256, 0, stream>>>(rowptr, bcur);
    bucket_fill_kernel<<<eb, 256, 0, stream>>>(row, col, bcur, packed);
    bucket_sort_kernel<<<NBUCKET, 256, 0, stream>>>(rowptr, packed, colsorted);
    tobf16_kernel<<<ub, 256, 0, stream>>>((const float4*)h_in, hb);

    for (int it = 0; it < KIT; ++it) {
        const float* cur = (it == 0) ? h_in : out;
        agg_kernel<<<gb, 256, 0, stream>>>((const uint4*)hb, rowptr, colsorted, S,
                                           maxslots + it * NSLOT);
        update_kernel<<<ub, 256, 0, stream>>>((const float4*)cur, (float4*)out, hb,
                                              (const float4*)S,
                                              maxslots + it * NSLOT);
    }
}

// Round 10
// 518.977 us; speedup vs baseline: 2.5037x; 2.5037x over previous
//
#include <hip/hip_runtime.h>

#define NN 100000
#define NE 1600000
#define DF 32
#define KIT 5
#define MU 0.01f
#define NSLOT 256
#define NV4 (NN * DF / 4)

#define SCAN_CHUNK 1024
#define SCAN_NB ((NN + SCAN_CHUNK - 1) / SCAN_CHUNK)  // 98 blocks

// ---------- one-time CSR build (row is iteration-invariant) ----------

__global__ __launch_bounds__(256) void zero_deg_kernel(int* __restrict__ deg) {
    int i = blockIdx.x * blockDim.x + threadIdx.x;
    if (i < NN) deg[i] = 0;
}

__global__ __launch_bounds__(256) void hist_kernel(const int* __restrict__ row,
                                                   int* __restrict__ deg) {
    int e = blockIdx.x * blockDim.x + threadIdx.x;
    if (e < NE) atomicAdd(&deg[row[e]], 1);
}

__global__ __launch_bounds__(256) void blocksum_kernel(const int* __restrict__ deg,
                                                       int* __restrict__ bsum) {
    const int t = threadIdx.x;
    const int base = blockIdx.x * SCAN_CHUNK + t * 4;
    int s = 0;
    #pragma unroll
    for (int i = 0; i < 4; ++i) {
        int idx = base + i;
        if (idx < NN) s += deg[idx];
    }
    #pragma unroll
    for (int m = 32; m > 0; m >>= 1) s += __shfl_xor(s, m, 64);
    __shared__ int sm[4];
    if ((t & 63) == 0) sm[t >> 6] = s;
    __syncthreads();
    if (t == 0) bsum[blockIdx.x] = sm[0] + sm[1] + sm[2] + sm[3];
}

__global__ __launch_bounds__(128) void scanbsum_kernel(int* __restrict__ bsum) {
    __shared__ int sh[SCAN_NB];
    const int t = threadIdx.x;
    if (t < SCAN_NB) sh[t] = bsum[t];
    __syncthreads();
    if (t == 0) {
        int run = 0;
        for (int i = 0; i < SCAN_NB; ++i) {
            int v = sh[i];
            sh[i] = run;
            run += v;
        }
    }
    __syncthreads();
    if (t < SCAN_NB) bsum[t] = sh[t];
}

__global__ __launch_bounds__(256) void scanfinal_kernel(const int* __restrict__ deg,
                                                        const int* __restrict__ bsum,
                                                        int* __restrict__ rowptr,
                                                        int* __restrict__ cursor) {
    const int t = threadIdx.x;
    const int base = blockIdx.x * SCAN_CHUNK + t * 4;
    int d[4];
    int s = 0;
    #pragma unroll
    for (int i = 0; i < 4; ++i) {
        int idx = base + i;
        d[i] = (idx < NN) ? deg[idx] : 0;
        s += d[i];
    }
    __shared__ int sh[256];
    sh[t] = s;
    __syncthreads();
    for (int off = 1; off < 256; off <<= 1) {
        int v = (t >= off) ? sh[t - off] : 0;
        __syncthreads();
        sh[t] += v;
        __syncthreads();
    }
    int run = bsum[blockIdx.x] + sh[t] - s;
    #pragma unroll
    for (int i = 0; i < 4; ++i) {
        int idx = base + i;
        if (idx < NN) {
            rowptr[idx] = run;
            cursor[idx] = run;
            run += d[i];
        }
    }
    if (blockIdx.x == 0 && t == 0) rowptr[NN] = NE;
}

// per-row cursors: 100k addresses, ~16 edges/address -> negligible contention
__global__ __launch_bounds__(256) void fill_kernel(const int* __restrict__ row,
                                                   const int* __restrict__ col,
                                                   int* __restrict__ cursor,
                                                   int* __restrict__ colsorted) {
    int e = blockIdx.x * blockDim.x + threadIdx.x;
    if (e < NE) {
        int pos = atomicAdd(&cursor[row[e]], 1);
        colsorted[pos] = col[e];
    }
}

// ---------- bf16 shadow helpers ----------

__device__ __forceinline__ unsigned int pack2bf(float a, float b) {
    unsigned int ua = __float_as_uint(a);
    unsigned int ub = __float_as_uint(b);
    return ((ua + 0x8000u) >> 16) | (((ub + 0x8000u) >> 16) << 16);
}

__device__ __forceinline__ void unpack8(uint4 v, float* f) {
    f[0] = __uint_as_float(v.x << 16);
    f[1] = __uint_as_float(v.x & 0xffff0000u);
    f[2] = __uint_as_float(v.y << 16);
    f[3] = __uint_as_float(v.y & 0xffff0000u);
    f[4] = __uint_as_float(v.z << 16);
    f[5] = __uint_as_float(v.z & 0xffff0000u);
    f[6] = __uint_as_float(v.w << 16);
    f[7] = __uint_as_float(v.w & 0xffff0000u);
}

__global__ __launch_bounds__(256) void tobf16_kernel(const float4* __restrict__ h,
                                                     uint2* __restrict__ hb) {
    int i = blockIdx.x * blockDim.x + threadIdx.x;
    if (i < NV4) {
        const float4 v = h[i];
        hb[i] = make_uint2(pack2bf(v.x, v.y), pack2bf(v.z, v.w));
    }
}

// ---------- per-iteration ----------

// One 32-lane group per NODE PAIR. lane = q(3b)*4 + f2(2b); a quad of lanes
// covers one 64B bf16 row (uint4/lane). All 10 loads for both nodes (2 col
// vectors, 2 own rows, 8 batch gathers) are issued before any consumption ->
// ~10 vmem in flight per group (R9 evidence: pairing cut agg ~75 -> ~50 us).
__global__ __launch_bounds__(256) void agg_kernel(const uint4* __restrict__ hb4,
                                                  const int* __restrict__ rowptr,
                                                  const int* __restrict__ colsorted,
                                                  float* __restrict__ S,
                                                  int* __restrict__ maxslots) {
    const int lane = threadIdx.x & 31;
    const int q = lane >> 2;
    const int f2 = lane & 3;
    const int pair = (blockIdx.x * blockDim.x + threadIdx.x) >> 5;
    const int n0 = pair * 2;
    const int n1 = n0 + 1;

    const int s0 = rowptr[n0];
    const int e0 = rowptr[n0 + 1];
    const int e1 = rowptr[n0 + 2];

    // issue all independent head loads
    const int i0 = s0 + lane;
    const int i1 = e0 + lane;
    const int ca = (i0 < e0) ? colsorted[i0] : n0;
    const int cb = (i1 < e1) ? colsorted[i1] : n1;
    const uint4 hru0 = hb4[n0 * 4 + f2];
    const uint4 hru1 = hb4[n1 * 4 + f2];

    // batch gathers for node0 then node1 (8 loads total)
    uint4 u0[4], u1[4];
    #pragma unroll
    for (int j = 0; j < 4; ++j) u0[j] = hb4[__shfl(ca, 8 * j + q, 32) * 4 + f2];
    #pragma unroll
    for (int j = 0; j < 4; ++j) u1[j] = hb4[__shfl(cb, 8 * j + q, 32) * 4 + f2];

    float hr0[8], hr1[8];
    unpack8(hru0, hr0);
    unpack8(hru1, hr1);

    float acc0[8], acc1[8];
    #pragma unroll
    for (int i = 0; i < 8; ++i) { acc0[i] = 0.0f; acc1[i] = 0.0f; }
    float nmax = 0.0f;

    // ---- node0 batch ----
    #pragma unroll
    for (int j = 0; j < 4; ++j) {
        float d[8];
        unpack8(u0[j], d);
        float s = 0.0f;
        #pragma unroll
        for (int i = 0; i < 8; ++i) {
            d[i] = hr0[i] - d[i];
            s = fmaf(d[i], d[i], s);
        }
        s += __shfl_xor(s, 1, 32);
        s += __shfl_xor(s, 2, 32);
        const float n = fmaxf(sqrtf(s), 1e-6f);
        nmax = fmaxf(nmax, n);
        const float w = rsqrtf(n);
        #pragma unroll
        for (int i = 0; i < 8; ++i) acc0[i] = fmaf(-d[i], w, acc0[i]);
    }
    // ---- node1 batch ----
    #pragma unroll
    for (int j = 0; j < 4; ++j) {
        float d[8];
        unpack8(u1[j], d);
        float s = 0.0f;
        #pragma unroll
        for (int i = 0; i < 8; ++i) {
            d[i] = hr1[i] - d[i];
            s = fmaf(d[i], d[i], s);
        }
        s += __shfl_xor(s, 1, 32);
        s += __shfl_xor(s, 2, 32);
        const float n = fmaxf(sqrtf(s), 1e-6f);
        nmax = fmaxf(nmax, n);
        const float w = rsqrtf(n);
        #pragma unroll
        for (int i = 0; i < 8; ++i) acc1[i] = fmaf(-d[i], w, acc1[i]);
    }

    // ---- rare tails (deg > 32) ----
    for (int k = s0 + 32; k < e0; k += 8) {
        const int ei = k + q;
        const int c = (ei < e0) ? colsorted[ei] : n0;
        const uint4 uu = hb4[c * 4 + f2];
        float d[8];
        unpack8(uu, d);
        float s = 0.0f;
        #pragma unroll
        for (int i = 0; i < 8; ++i) {
            d[i] = hr0[i] - d[i];
            s = fmaf(d[i], d[i], s);
        }
        s += __shfl_xor(s, 1, 32);
        s += __shfl_xor(s, 2, 32);
        const float n = fmaxf(sqrtf(s), 1e-6f);
        nmax = fmaxf(nmax, n);
        const float w = rsqrtf(n);
        #pragma unroll
        for (int i = 0; i < 8; ++i) acc0[i] = fmaf(-d[i], w, acc0[i]);
    }
    for (int k = e0 + 32; k < e1; k += 8) {
        const int ei = k + q;
        const int c = (ei < e1) ? colsorted[ei] : n1;
        const uint4 uu = hb4[c * 4 + f2];
        float d[8];
        unpack8(uu, d);
        float s = 0.0f;
        #pragma unroll
        for (int i = 0; i < 8; ++i) {
            d[i] = hr1[i] - d[i];
            s = fmaf(d[i], d[i], s);
        }
        s += __shfl_xor(s, 1, 32);
        s += __shfl_xor(s, 2, 32);
        const float n = fmaxf(sqrtf(s), 1e-6f);
        nmax = fmaxf(nmax, n);
        const float w = rsqrtf(n);
        #pragma unroll
        for (int i = 0; i < 8; ++i) acc1[i] = fmaf(-d[i], w, acc1[i]);
    }

    // cross-quad reduce (quads hold different edges, same feats)
    #pragma unroll
    for (int m = 4; m < 32; m <<= 1) {
        #pragma unroll
        for (int i = 0; i < 8; ++i) {
            acc0[i] += __shfl_xor(acc0[i], m, 32);
            acc1[i] += __shfl_xor(acc1[i], m, 32);
        }
    }
    if (q == 0) {
        ((float4*)S)[n0 * 8 + f2 * 2] = make_float4(acc0[0], acc0[1], acc0[2], acc0[3]);
        ((float4*)S)[n0 * 8 + f2 * 2 + 1] = make_float4(acc0[4], acc0[5], acc0[6], acc0[7]);
        ((float4*)S)[n1 * 8 + f2 * 2] = make_float4(acc1[0], acc1[1], acc1[2], acc1[3]);
        ((float4*)S)[n1 * 8 + f2 * 2 + 1] = make_float4(acc1[4], acc1[5], acc1[6], acc1[7]);
    }

    // group max -> wave max -> spread atomic
    nmax = fmaxf(nmax, __shfl_xor(nmax, 4, 32));
    nmax = fmaxf(nmax, __shfl_xor(nmax, 8, 32));
    nmax = fmaxf(nmax, __shfl_xor(nmax, 16, 32));
    nmax = fmaxf(nmax, __shfl_xor(nmax, 32, 64));
    if ((threadIdx.x & 63) == 0) {
        // positive floats order like ints; 0xAA poison is negative -> loses
        atomicMax(&maxslots[blockIdx.x & (NSLOT - 1)], __float_as_int(nmax));
    }
}

// h_out = h_in - MU*sqrt(M)*S (fp32), plus refresh of the bf16 shadow.
__global__ __launch_bounds__(256) void update_kernel(const float4* __restrict__ hcur,
                                                     float4* __restrict__ hnxt,
                                                     uint2* __restrict__ hb,
                                                     const float4* __restrict__ S,
                                                     const int* __restrict__ slots) {
    const int t = threadIdx.x;
    int v = slots[t];
    #pragma unroll
    for (int m = 32; m > 0; m >>= 1) v = max(v, __shfl_xor(v, m, 64));
    __shared__ int sm[4];
    __shared__ float sscale;
    if ((t & 63) == 0) sm[t >> 6] = v;
    __syncthreads();
    if (t == 0) {
        int bm = max(max(sm[0], sm[1]), max(sm[2], sm[3]));
        sscale = MU * sqrtf(__int_as_float(bm));
    }
    __syncthreads();
    const float scale = sscale;
    const int i = blockIdx.x * blockDim.x + t;
    if (i < NV4) {
        const float4 hv = hcur[i];
        const float4 sv = S[i];
        float4 o;
        o.x = hv.x - scale * sv.x;
        o.y = hv.y - scale * sv.y;
        o.z = hv.z - scale * sv.z;
        o.w = hv.w - scale * sv.w;
        hnxt[i] = o;
        hb[i] = make_uint2(pack2bf(o.x, o.y), pack2bf(o.z, o.w));
    }
}

extern "C" void kernel_launch(void* const* d_in, const int* in_sizes, int n_in,
                              void* d_out, int out_size, void* d_ws, size_t ws_size,
                              hipStream_t stream) {
    const float* h_in = (const float*)d_in[0];
    const int* row = (const int*)d_in[1];
    const int* col = row + NE;
    float* out = (float*)d_out;

    float* S = (float*)d_ws;                        // NN*DF f32
    int* maxslots = (int*)(S + NN * DF);            // KIT*NSLOT
    int* deg = maxslots + KIT * NSLOT;              // NN
    int* rowptr = deg + NN;                         // NN+1
    int* cursor = rowptr + NN + 1;                  // NN
    int* bsum = cursor + NN;                        // SCAN_NB
    int* colsorted = bsum + SCAN_NB;                // NE
    uintptr_t p = (uintptr_t)(colsorted + NE);
    p = (p + 15) & ~(uintptr_t)15;
    uint2* hb = (uint2*)p;                          // NN*DF bf16 = 6.4 MB

    const int eb = (NE + 255) / 256;
    const int nb = (NN + 255) / 256;
    const int gb = (NN / 2 * 32 + 255) / 256;       // 6250
    const int ub = (NV4 + 255) / 256;               // 3125

    zero_deg_kernel<<<nb, 256, 0, stream>>>(deg);
    hist_kernel<<<eb, 256, 0, stream>>>(row, deg);
    blocksum_kernel<<<SCAN_NB, 256, 0, stream>>>(deg, bsum);
    scanbsum_kernel<<<1, 128, 0, stream>>>(bsum);
    scanfinal_kernel<<<SCAN_NB, 256, 0, stream>>>(deg, bsum, rowptr, cursor);
    fill_kernel<<<eb, 256, 0, stream>>>(row, col, cursor, colsorted);
    tobf16_kernel<<<ub, 256, 0, stream>>>((const float4*)h_in, hb);

    for (int it = 0; it < KIT; ++it) {
        const float* cur = (it == 0) ? h_in : out;
        agg_kernel<<<gb, 256, 0, stream>>>((const uint4*)hb, rowptr, colsorted, S,
                                           maxslots + it * NSLOT);
        update_kernel<<<ub, 256, 0, stream>>>((const float4*)cur, (float4*)out, hb,
                                              (const float4*)S,
                                              maxslots + it * NSLOT);
    }
}